// Round 4
// baseline (595.461 us; speedup 1.0000x reference)
//
#include <hip/hip_runtime.h>
#include <math.h>

#define NROWS 8192   // BATCH*NODE
#define DIM   128
#define FEAT  256
#define KSPLIT 8
#define KCH   (NROWS / KSPLIT)  // 1024

typedef __attribute__((ext_vector_type(8))) __bf16 bf16x8;
typedef __attribute__((ext_vector_type(8))) unsigned short u16x8;
typedef __attribute__((ext_vector_type(4))) float f32x4;

__device__ __forceinline__ float bf2f(unsigned short h) {
  return __uint_as_float(((unsigned)h) << 16);
}
__device__ __forceinline__ unsigned short f2bf(float f) {
  unsigned u = __float_as_uint(f);
  return (unsigned short)((u + 0x7fff + ((u >> 16) & 1)) >> 16);  // RNE
}
__device__ __forceinline__ float ldv(const void* p, size_t i, int is32) {
  return is32 ? ((const float*)p)[i] : bf2f(((const unsigned short*)p)[i]);
}
__device__ __forceinline__ void async16(const void* g, void* l) {
  __builtin_amdgcn_global_load_lds(
      (const __attribute__((address_space(1))) void*)g,
      (__attribute__((address_space(3))) void*)l, 16, 0, 0);
}
__device__ __forceinline__ f32x4 mfma16(bf16x8 a, bf16x8 b, f32x4 c) {
  return __builtin_amdgcn_mfma_f32_16x16x32_bf16(a, b, c, 0, 0, 0);
}

// ---------------------------------------------------------------------------
// dtype detect: f32 L -> even shorts are uniform mantissa bits (~25% exp>=192)
// ---------------------------------------------------------------------------
__global__ void detect_kernel(const unsigned short* __restrict__ L,
                              int* __restrict__ flag)
{
  __shared__ int cnt;
  if (threadIdx.x == 0) cnt = 0;
  __syncthreads();
  int c = 0;
  for (int i = 0; i < 16; i++) {
    unsigned short s = L[2 * (threadIdx.x + 256 * i)];
    if (((s >> 7) & 0xFF) >= 192) c++;
  }
  atomicAdd(&cnt, c);
  __syncthreads();
  if (threadIdx.x == 0) *flag = (cnt > 4) ? 1 : 0;
}

// ---------------------------------------------------------------------------
// trans+stats: src (8192x128) -> xT (128x8192 bf16), optional elu + xcopy,
// fused column stats -> stats[0..128],[256..384]. 128 blocks x 64 rows.
// src dtype: f32-or-bf16 per *flag when flag_src!=0, else bf16.
// ---------------------------------------------------------------------------
__global__ __launch_bounds__(256) void trans_stats(
    const void* __restrict__ src, const int* __restrict__ flag_src,
    unsigned short* __restrict__ xT, unsigned short* __restrict__ xcopy,
    float* __restrict__ stats, int do_elu)
{
  __shared__ __align__(16) unsigned short T[64 * 136];
  __shared__ float xs[128], xq[128];
  const int is32 = flag_src ? *flag_src : 0;
  const int tid = threadIdx.x;
  const int r0 = blockIdx.x * 64;
  if (tid < 128) { xs[tid] = 0.f; xq[tid] = 0.f; }

  float ls[8], lq[8];
  #pragma unroll
  for (int e = 0; e < 8; e++) { ls[e] = 0.f; lq[e] = 0.f; }

  #pragma unroll
  for (int i = 0; i < 4; i++) {
    const int c = tid + 256 * i;           // 0..1023
    const int rr = c >> 4, cg = c & 15;
    const size_t base = (size_t)(r0 + rr) * DIM + cg * 8;
    u16x8 v;
    #pragma unroll
    for (int e = 0; e < 8; e++) {
      float f = ldv(src, base + e, is32);
      if (do_elu) f = f > 0.f ? f : expm1f(f);
      v[e] = f2bf(f);
      float fb = bf2f(v[e]);
      ls[e] += fb; lq[e] += fb * fb;
    }
    if (xcopy) *(u16x8*)(xcopy + base) = v;
    *(u16x8*)(T + rr * 136 + cg * 8) = v;
  }
  __syncthreads();   // T + xs/xq-zero visible

  #pragma unroll
  for (int e = 0; e < 8; e++) {
    atomicAdd(&xs[(tid & 15) * 8 + e], ls[e]);
    atomicAdd(&xq[(tid & 15) * 8 + e], lq[e]);
  }

  #pragma unroll
  for (int i = 0; i < 4; i++) {
    const int c = tid + 256 * i;
    const int n = c >> 3, mg = c & 7;
    u16x8 v;
    #pragma unroll
    for (int e = 0; e < 8; e++) v[e] = T[(mg * 8 + e) * 136 + n];
    *(u16x8*)(xT + (size_t)n * NROWS + r0 + mg * 8) = v;
  }
  __syncthreads();
  if (tid < 128) {
    atomicAdd(&stats[tid], xs[tid]);
    atomicAdd(&stats[256 + tid], xq[tid]);
  }
}

// ---------------------------------------------------------------------------
// GEMM1 (split-K, atomic accumulate): Lx += L[m0:+128, k0:+1024] @ x
// A = L (f32 or bf16): register staging + cvt + ds_write_b128
// B = xT bf16: global_load_lds width-16. Verified XOR k-group swizzle.
// ---------------------------------------------------------------------------
__global__ __launch_bounds__(256) void gemm1_splitk(
    const void* __restrict__ Lraw,           // 8192 x 8192 (f32 or bf16)
    const unsigned short* __restrict__ xT,   // 128 x 8192 bf16
    float* __restrict__ Lx,                  // 8192 x 128 f32 (pre-zeroed)
    const int* __restrict__ flag)
{
  __shared__ __align__(16) unsigned short As[128 * 32];
  __shared__ __align__(16) unsigned short Bs[128 * 32];
  const int is32 = *flag;
  const int tid  = threadIdx.x;
  const int lane = tid & 63;
  const int wave = tid >> 6;
  const int m0 = blockIdx.x * 128;
  const int k0 = blockIdx.y * KCH;

  // A chunks: tid and tid+256; chunk c -> row=c>>2, slot=c&3 holds
  // global k-group kg = slot ^ ((row>>1)&3)
  const int c0 = tid, c1 = tid + 256;
  const int r0s = c0 >> 2, kg0 = (c0 & 3) ^ ((r0s >> 1) & 3);
  const int r1s = c1 >> 2, kg1 = (c1 & 3) ^ ((r1s >> 1) & 3);
  size_t eA0 = (size_t)(m0 + r0s) * NROWS + k0 + kg0 * 8;
  size_t eA1 = (size_t)(m0 + r1s) * NROWS + k0 + kg1 * 8;
  unsigned short* sA0 = As + r0s * 32 + (c0 & 3) * 8;
  unsigned short* sA1 = As + r1s * 32 + (c1 & 3) * 8;
  // B chunks via async16 (wave-uniform base + lane*16 ordering)
  const int cb0 = wave * 128 + lane, cb1 = cb0 + 64;
  const int rb0 = cb0 >> 2, kb0 = (cb0 & 3) ^ ((rb0 >> 1) & 3);
  const int rb1 = cb1 >> 2, kb1 = (cb1 & 3) ^ ((rb1 >> 1) & 3);
  const unsigned short* gB0 = xT + (size_t)rb0 * NROWS + k0 + kb0 * 8;
  const unsigned short* gB1 = xT + (size_t)rb1 * NROWS + k0 + kb1 * 8;
  unsigned short* lB0 = Bs + wave * 1024;
  unsigned short* lB1 = Bs + wave * 1024 + 512;

  const int ln = lane & 15, quad = lane >> 4;
  const int mq = (wave & 1) * 64, nq = (wave >> 1) * 64;
  const int akg = quad ^ ((ln >> 1) & 3);

  f32x4 acc[4][4];
  #pragma unroll
  for (int i = 0; i < 4; i++)
    #pragma unroll
    for (int j = 0; j < 4; j++)
      acc[i][j] = (f32x4){0.f, 0.f, 0.f, 0.f};

  for (int kb = 0; kb < KCH / 32; ++kb) {
    u16x8 a0, a1;
    if (is32) {
      const float* Lf = (const float*)Lraw;
      f32x4 p0 = *(const f32x4*)(Lf + eA0), p1 = *(const f32x4*)(Lf + eA0 + 4);
      f32x4 q0 = *(const f32x4*)(Lf + eA1), q1 = *(const f32x4*)(Lf + eA1 + 4);
      #pragma unroll
      for (int e = 0; e < 4; e++) {
        a0[e] = f2bf(p0[e]); a0[e + 4] = f2bf(p1[e]);
        a1[e] = f2bf(q0[e]); a1[e + 4] = f2bf(q1[e]);
      }
    } else {
      const unsigned short* Lh = (const unsigned short*)Lraw;
      a0 = *(const u16x8*)(Lh + eA0);
      a1 = *(const u16x8*)(Lh + eA1);
    }
    eA0 += 32; eA1 += 32;

    __syncthreads();   // previous iteration's LDS readers done
    *(u16x8*)sA0 = a0;
    *(u16x8*)sA1 = a1;
    async16(gB0, lB0); async16(gB1, lB1);
    gB0 += 32; gB1 += 32;
    __syncthreads();   // drains vmcnt (B) + lgkm (A)

    bf16x8 af[4], bfr[4];
    #pragma unroll
    for (int i = 0; i < 4; i++)
      af[i] = *(const bf16x8*)(As + (mq + i * 16 + ln) * 32 + akg * 8);
    #pragma unroll
    for (int j = 0; j < 4; j++)
      bfr[j] = *(const bf16x8*)(Bs + (nq + j * 16 + ln) * 32 + akg * 8);
    #pragma unroll
    for (int i = 0; i < 4; i++)
      #pragma unroll
      for (int j = 0; j < 4; j++)
        acc[i][j] = mfma16(af[i], bfr[j], acc[i][j]);
  }

  #pragma unroll
  for (int i = 0; i < 4; i++) {
    const int gmb = m0 + mq + i * 16 + quad * 4;
    #pragma unroll
    for (int j = 0; j < 4; j++) {
      const int gn = nq + j * 16 + ln;
      #pragma unroll
      for (int r = 0; r < 4; r++)
        atomicAdd(&Lx[(size_t)(gmb + r) * DIM + gn], acc[i][j][r]);
    }
  }
}

// ---------------------------------------------------------------------------
// Lx f32 -> Lxb bf16 + column stats (features 128..255). 256 blocks.
// ---------------------------------------------------------------------------
__global__ __launch_bounds__(256) void lx_stats(
    const float* __restrict__ Lx, unsigned short* __restrict__ Lxb,
    float* __restrict__ stats)
{
  __shared__ float rs[256], rq[256];
  const int tid = threadIdx.x;
  const int col = tid & 127, rhalf = tid >> 7;
  const int rbase = blockIdx.x * 32 + rhalf * 16;
  float s = 0.f, q = 0.f;
  #pragma unroll
  for (int i = 0; i < 16; i++) {
    const size_t idx = (size_t)(rbase + i) * DIM + col;
    float v = Lx[idx];
    Lxb[idx] = f2bf(v);
    s += v; q += v * v;
  }
  rs[tid] = s; rq[tid] = q;
  __syncthreads();
  if (rhalf == 0) {
    atomicAdd(&stats[128 + col], rs[tid] + rs[tid + 128]);
    atomicAdd(&stats[384 + col], rq[tid] + rq[tid + 128]);
  }
}

// ---------------------------------------------------------------------------
// fold BN into FC (params f32-or-bf16 per flag)
// ---------------------------------------------------------------------------
__global__ void prep_kernel(const float* __restrict__ stats,
                            const void* __restrict__ gamma,
                            const void* __restrict__ beta,
                            const void* __restrict__ w,
                            const void* __restrict__ bias,
                            unsigned short* __restrict__ weff,
                            float* __restrict__ beff,
                            const int* __restrict__ flag)
{
  const int is32 = *flag;
  const int k = blockIdx.x;   // 0..127
  const int j = threadIdx.x;  // 0..255
  const float inv = 1.f / 8192.f;
  float mu = stats[j] * inv;
  float var = fmaxf(stats[256 + j] * inv - mu * mu, 0.f);
  float s = ldv(gamma, j, is32) * rsqrtf(var + 1e-5f);
  float wv = ldv(w, (size_t)k * FEAT + j, is32);
  weff[(size_t)k * FEAT + j] = f2bf(wv * s);
  float term = (ldv(beta, j, is32) - mu * s) * wv;
  __shared__ float red[256];
  red[j] = term;
  __syncthreads();
  for (int off = 128; off > 0; off >>= 1) {
    if (j < off) red[j] += red[j + off];
    __syncthreads();
  }
  if (j == 0) beff[k] = ldv(bias, k, is32) + red[0];
}

// ---------------------------------------------------------------------------
// GEMM2: out = [x | Lxb] @ weff.T + beff ; mode0: elu->bf16; mode1: +resid
// ---------------------------------------------------------------------------
__global__ __launch_bounds__(256) void gemm2_fc(
    const unsigned short* __restrict__ xb,
    const unsigned short* __restrict__ Lxb,
    const unsigned short* __restrict__ weff,
    const float* __restrict__ beff,
    const void* __restrict__ resid,
    void* __restrict__ outv,
    int mode, const int* __restrict__ flag)
{
  __shared__ __align__(16) unsigned short As[32 * 264];
  const int is32 = *flag;
  const int tid = threadIdx.x;
  const int lane = tid & 63, wave = tid >> 6;
  const int m0 = blockIdx.x * 32;

  #pragma unroll
  for (int i = 0; i < 4; i++) {
    const int c = tid + 256 * i;
    const int mr = c >> 5, ch = c & 31;
    const unsigned short* src =
        (ch < 16) ? (xb  + (size_t)(m0 + mr) * DIM + ch * 8)
                  : (Lxb + (size_t)(m0 + mr) * DIM + (ch - 16) * 8);
    *(u16x8*)(As + mr * 264 + ch * 8) = *(const u16x8*)src;
  }
  __syncthreads();

  const int ln = lane & 15, quad = lane >> 4;
  const int nq = wave * 32;
  f32x4 acc[2][2];
  #pragma unroll
  for (int i = 0; i < 2; i++)
    #pragma unroll
    for (int j = 0; j < 2; j++)
      acc[i][j] = (f32x4){0.f, 0.f, 0.f, 0.f};

  #pragma unroll
  for (int ks = 0; ks < 8; ks++) {
    bf16x8 af[2], bfr[2];
    #pragma unroll
    for (int i = 0; i < 2; i++)
      af[i] = *(const bf16x8*)(As + (i * 16 + ln) * 264 + ks * 32 + quad * 8);
    #pragma unroll
    for (int j = 0; j < 2; j++)
      bfr[j] = *(const bf16x8*)(weff + (size_t)(nq + j * 16 + ln) * FEAT +
                                ks * 32 + quad * 8);
    #pragma unroll
    for (int i = 0; i < 2; i++)
      #pragma unroll
      for (int j = 0; j < 2; j++)
        acc[i][j] = mfma16(af[i], bfr[j], acc[i][j]);
  }

  #pragma unroll
  for (int j = 0; j < 2; j++) {
    const int gn = nq + j * 16 + ln;
    const float bb = beff[gn];
    #pragma unroll
    for (int i = 0; i < 2; i++) {
      #pragma unroll
      for (int r = 0; r < 4; r++) {
        const int gm = m0 + i * 16 + quad * 4 + r;
        float v = acc[i][j][r] + bb;
        const size_t idx = (size_t)gm * DIM + gn;
        if (mode == 0) {
          v = v > 0.f ? v : expm1f(v);
          ((unsigned short*)outv)[idx] = f2bf(v);
        } else {
          v += ldv(resid, idx, is32);
          if (is32) ((float*)outv)[idx] = v;
          else      ((unsigned short*)outv)[idx] = f2bf(v);
        }
      }
    }
  }
}

// ---------------------------------------------------------------------------
extern "C" void kernel_launch(void* const* d_in, const int* in_sizes, int n_in,
                              void* d_out, int out_size, void* d_ws, size_t ws_size,
                              hipStream_t stream) {
  const void* Lm   = d_in[0];
  const void* inp  = d_in[2];
  const void* bn0g = d_in[3];
  const void* bn0b = d_in[4];
  const void* fc0w = d_in[5];
  const void* fc0b = d_in[6];
  const void* bn1g = d_in[7];
  const void* bn1b = d_in[8];
  const void* fc1w = d_in[9];
  const void* fc1b = d_in[10];

  char* ws = (char*)d_ws;
  unsigned short* x0   = (unsigned short*)(ws);                    // 2 MB
  unsigned short* xT   = (unsigned short*)(ws + (2 << 20));        // 2 MB
  float*          Lx   = (float*)         (ws + (4 << 20));        // 4 MB
  float*          stats= (float*)         (ws + (8 << 20));        // 2 KB
  unsigned short* Lxb  = (unsigned short*)(ws + (9 << 20));        // 2 MB
  unsigned short* x1   = (unsigned short*)(ws + (11 << 20));       // 2 MB
  int*            flag = (int*)           (ws + (13 << 20));
  float*          beff = (float*)         (ws + (13 << 20) + 4096);
  unsigned short* weff = (unsigned short*)(ws + (13 << 20) + 8192); // 64 KB

  detect_kernel<<<1, 256, 0, stream>>>((const unsigned short*)Lm, flag);

  // ---- block 0 ----
  hipMemsetAsync(Lx, 0, (4 << 20), stream);
  hipMemsetAsync(stats, 0, 2048, stream);
  trans_stats<<<128, 256, 0, stream>>>(inp, flag, xT, x0, stats, 1);
  gemm1_splitk<<<dim3(64, KSPLIT), 256, 0, stream>>>(Lm, xT, Lx, flag);
  lx_stats<<<256, 256, 0, stream>>>(Lx, Lxb, stats);
  prep_kernel<<<128, 256, 0, stream>>>(stats, bn0g, bn0b, fc0w, fc0b,
                                       weff, beff, flag);
  gemm2_fc<<<256, 256, 0, stream>>>(x0, Lxb, weff, beff, nullptr, x1, 0, flag);

  // ---- block 1 ----
  hipMemsetAsync(Lx, 0, (4 << 20), stream);
  hipMemsetAsync(stats, 0, 2048, stream);
  trans_stats<<<128, 256, 0, stream>>>(x1, nullptr, xT, nullptr, stats, 0);
  gemm1_splitk<<<dim3(64, KSPLIT), 256, 0, stream>>>(Lm, xT, Lx, flag);
  lx_stats<<<256, 256, 0, stream>>>(Lx, Lxb, stats);
  prep_kernel<<<128, 256, 0, stream>>>(stats, bn1g, bn1b, fc1w, fc1b,
                                       weff, beff, flag);
  gemm2_fc<<<256, 256, 0, stream>>>(x1, Lxb, weff, beff, inp, d_out, 1, flag);
}